// Round 4
// baseline (4820.550 us; speedup 1.0000x reference)
//
#include <hip/hip_runtime.h>

#define T_STEPS 1024
#define BATCH   256
#define DIM     128
#define HID     256
#define NSLICE  8                  // blocks per batch-group (h-slice split)
#define BT      16                 // batch tile per group
#define NGROUP  (BATCH / BT)       // 16
#define NBLOCK  (NGROUP * NSLICE)  // 128
#define JW      (HID / NSLICE)     // 32 h-indices per block

// LDS layout (bytes)
#define U_OFF    0        // [128][256] bf16, swizzled (U rows q*JW + jj within slice)
#define W_OFF    65536    // [128][128] bf16, swizzled
#define WD_OFF   98304    // [32][256]  bf16, swizzled
#define H_OFF    114688   // [16][256]  bf16, swizzled (h tile)
#define C_OFF    122880   // [16][256]  bf16, swizzled (c tile)
#define GST_OFF  131072   // [16][132] f32 gates staging (padded stride)
#define CS0_OFF  139520   // [16][33]  f32 Cs partial 0
#define CS1_OFF  141632   // [16][33]  f32 Cs partial 1
#define SMEM_TOTAL 143744

typedef float f32x4 __attribute__((ext_vector_type(4)));
typedef short bf16x8 __attribute__((ext_vector_type(8)));

__device__ __forceinline__ unsigned short f2bf(float f) {
    union { float f; unsigned u; } v; v.f = f;
    unsigned r = (v.u + 0x7fffu + ((v.u >> 16) & 1u)) >> 16;   // RNE
    return (unsigned short)r;
}
__device__ __forceinline__ float sigm(float v) { return 1.0f / (1.0f + __expf(-v)); }
__device__ __forceinline__ float tanh_fast(float v) {
    const float e = __expf(2.0f * v);
    return 1.0f - 2.0f / (e + 1.0f);
}

// flags[(g*8+s)*32 + w] : producer block (g,s), wave w published step value
#define FLAG_IDX(g, s, w) (((g) * 8 + (s)) * 32 + (w))

__global__ __launch_bounds__(512)
void tlstm_kernel(const float* __restrict__ x,
                  const float* __restrict__ dts,
                  const float* __restrict__ h0,
                  const float* __restrict__ c0,
                  const float* __restrict__ W,
                  const float* __restrict__ U,
                  const float* __restrict__ bvec,
                  const float* __restrict__ Wd,
                  const float* __restrict__ bd,
                  float* __restrict__ out,
                  unsigned int* flags,
                  unsigned int* hb32,
                  unsigned int* cb32)
{
    extern __shared__ char smem[];
    float* gates_st = (float*)(smem + GST_OFF);
    float* cs0      = (float*)(smem + CS0_OFF);
    float* cs1      = (float*)(smem + CS1_OFF);

    const int tid = threadIdx.x;
    const int g  = blockIdx.x / NSLICE;   // batch group
    const int s  = blockIdx.x % NSLICE;   // h-slice
    const int bb = g * BT;
    const int jb = s * JW;

    const int lane = tid & 63;
    const int wid  = tid >> 6;     // 0..7
    const int lrow = lane & 15;    // A-row(batch) / B-col(weight row) / D-col
    const int lkg  = lane >> 4;    // K-group 0..3
    const int n0   = wid << 4;     // gates column base for this wave

    const int b_ = tid >> 5;   // 0..15 batch row (elementwise + publish mapping)
    const int jj = tid & 31;   // 0..31 h-index within slice

    // ---- one-time: weights -> LDS (bf16, XOR-swizzled rows: byte ^= (row&7)<<4) ----
    for (int idx = tid; idx < 128 * 256; idx += 512) {
        const int r = idx >> 8, k = idx & 255;
        const int urow = ((r >> 5) * HID) + jb + (r & 31);   // q*H + jb + jj
        int bo = (r << 9) + (k << 1); bo ^= (r & 7) << 4;
        *(unsigned short*)(smem + U_OFF + bo) = f2bf(U[(size_t)urow * HID + k]);
    }
    for (int idx = tid; idx < 128 * 128; idx += 512) {
        const int r = idx >> 7, k = idx & 127;
        const int wrow = ((r >> 5) * HID) + jb + (r & 31);
        int bo = (r << 8) + (k << 1); bo ^= (r & 7) << 4;
        *(unsigned short*)(smem + W_OFF + bo) = f2bf(W[(size_t)wrow * DIM + k]);
    }
    for (int idx = tid; idx < 32 * 256; idx += 512) {
        const int r = idx >> 8, k = idx & 255;
        int bo = (r << 9) + (k << 1); bo ^= (r & 7) << 4;
        *(unsigned short*)(smem + WD_OFF + bo) = f2bf(Wd[(size_t)(jb + r) * HID + k]);
    }

    // ---- per-thread constants ----
    const float bI = bvec[jb + jj];
    const float bF = bvec[HID + jb + jj];
    const float bG = bvec[2 * HID + jb + jj];
    const float bO = bvec[3 * HID + jb + jj];
    const float bD = bd[jb + jj];

    // ---- prefetch x(0) raw + dt(0) ----
    float4 xr[8];
    float dt_cur;
    {
        const float* xp = x + ((size_t)0 * BATCH + bb + lrow) * DIM + (lkg << 3);
        #pragma unroll
        for (int kc = 0; kc < 4; ++kc) {
            xr[2 * kc]     = *(const float4*)(xp + kc * 32);
            xr[2 * kc + 1] = *(const float4*)(xp + kc * 32 + 4);
        }
        dt_cur = dts[(size_t)(bb + b_) * T_STEPS + 0];
    }

    // ---- init: c in register + publish h0/c0 into buf0; per-wave flag = 1 ----
    float c_reg;
    {
        const float h0v = h0[(size_t)(bb + b_) * HID + jb + jj];
        const float c0v = c0[(size_t)(bb + b_) * HID + jb + jj];
        c_reg = c0v;
        const unsigned short hb16 = f2bf(h0v), cb16 = f2bf(c0v);
        const int oh = __shfl_xor((int)hb16, 1);
        const int oc = __shfl_xor((int)cb16, 1);
        if ((jj & 1) == 0) {
            const unsigned int hw = (unsigned)hb16 | ((unsigned)oh << 16);
            const unsigned int cw = (unsigned)cb16 | ((unsigned)oc << 16);
            const int ei = (((0 * NGROUP + g) * 8 + s) * 16 + b_) * 16 + (jj >> 1);
            __hip_atomic_store(hb32 + ei, hw, __ATOMIC_RELAXED, __HIP_MEMORY_SCOPE_AGENT);
            __hip_atomic_store(cb32 + ei, cw, __ATOMIC_RELAXED, __HIP_MEMORY_SCOPE_AGENT);
        }
    }
    asm volatile("s_waitcnt vmcnt(0)" ::: "memory");
    if (lane == 0)
        __hip_atomic_store(flags + FLAG_IDX(g, s, wid), 1u,
                           __ATOMIC_RELAXED, __HIP_MEMORY_SCOPE_AGENT);

    for (int t = 0; t < T_STEPS; ++t) {
        const int cur = t & 1;

        // ---- (1) x-dependent work first: convert + x@W^T MFMAs (no flag dep) ----
        bf16x8 xa[4];
        #pragma unroll
        for (int kc = 0; kc < 4; ++kc) {
            const float4 f0 = xr[2 * kc];
            const float4 f1 = xr[2 * kc + 1];
            bf16x8 a;
            a[0] = (short)f2bf(f0.x); a[1] = (short)f2bf(f0.y);
            a[2] = (short)f2bf(f0.z); a[3] = (short)f2bf(f0.w);
            a[4] = (short)f2bf(f1.x); a[5] = (short)f2bf(f1.y);
            a[6] = (short)f2bf(f1.z); a[7] = (short)f2bf(f1.w);
            xa[kc] = a;
        }
        f32x4 accX = {0.f, 0.f, 0.f, 0.f};
        {
            const int wr = n0 + lrow;
            #pragma unroll
            for (int kc = 0; kc < 4; ++kc) {       // x @ W^T, K=128
                int wo = (wr << 8) + ((kc * 32 + (lkg << 3)) << 1); wo ^= (wr & 7) << 4;
                const bf16x8 wv = *(const bf16x8*)(smem + W_OFF + wo);
                accX = __builtin_amdgcn_mfma_f32_16x16x32_bf16(xa[kc], wv, accX, 0, 0, 0);
            }
        }

        // ---- (2) wave w polls the 8 wave-flags of producer block (g, w) ----
        {
            const unsigned target = (unsigned)(t + 1);
            const unsigned* fb = flags + FLAG_IDX(g, wid, 0);
            unsigned fl = target;
            do {
                if (lane < 8)
                    fl = __hip_atomic_load(fb + lane, __ATOMIC_RELAXED, __HIP_MEMORY_SCOPE_AGENT);
            } while (__any((int)(fl < target)));
        }
        asm volatile("" ::: "memory");
        __builtin_amdgcn_sched_barrier(0);

        // ---- (3) stage slice w of h,c (1 KB each, contiguous) into LDS ----
        {
            const int boff = ((cur * NGROUP + g) * 8 + wid) * 256;   // u32 offset
            const unsigned long long* hq = (const unsigned long long*)(hb32 + boff);
            const unsigned long long* cq = (const unsigned long long*)(cb32 + boff);
            const unsigned long long h1 = __hip_atomic_load(hq + lane,      __ATOMIC_RELAXED, __HIP_MEMORY_SCOPE_AGENT);
            const unsigned long long h2 = __hip_atomic_load(hq + lane + 64, __ATOMIC_RELAXED, __HIP_MEMORY_SCOPE_AGENT);
            const unsigned long long c1 = __hip_atomic_load(cq + lane,      __ATOMIC_RELAXED, __HIP_MEMORY_SCOPE_AGENT);
            const unsigned long long c2 = __hip_atomic_load(cq + lane + 64, __ATOMIC_RELAXED, __HIP_MEMORY_SCOPE_AGENT);
            const int r1 = lane >> 3, r2 = 8 + (lane >> 3);
            const int cb = (wid << 6) + ((lane & 7) << 3);           // byte col base
            int bo1 = (r1 << 9) + cb; bo1 ^= (r1 & 7) << 4;
            int bo2 = (r2 << 9) + cb; bo2 ^= (r2 & 7) << 4;
            *(unsigned long long*)(smem + H_OFF + bo1) = h1;
            *(unsigned long long*)(smem + H_OFF + bo2) = h2;
            *(unsigned long long*)(smem + C_OFF + bo1) = c1;
            *(unsigned long long*)(smem + C_OFF + bo2) = c2;
        }
        __syncthreads();   // #1: all slices staged

        // ---- (4) h @ U^T (all waves) + c @ Wd^T (waves 0-3, split N x K-half) ----
        f32x4 accH = {0.f, 0.f, 0.f, 0.f};
        {
            const int wr = n0 + lrow;
            #pragma unroll
            for (int kc = 0; kc < 8; ++kc) {       // h @ U^T, K=256
                int ao = (lrow << 9) + ((kc * 32 + (lkg << 3)) << 1); ao ^= (lrow & 7) << 4;
                const bf16x8 av = *(const bf16x8*)(smem + H_OFF + ao);
                int uo = (wr << 9) + ((kc * 32 + (lkg << 3)) << 1); uo ^= (wr & 7) << 4;
                const bf16x8 uv = *(const bf16x8*)(smem + U_OFF + uo);
                accH = __builtin_amdgcn_mfma_f32_16x16x32_bf16(av, uv, accH, 0, 0, 0);
            }
        }
        if (wid < 4) {
            f32x4 accC = {0.f, 0.f, 0.f, 0.f};
            const int nt = wid >> 1;               // N-tile 0/1 (cols 0-15 / 16-31)
            const int kh = wid & 1;                // K-half
            const int wr = (nt << 4) + lrow;
            #pragma unroll
            for (int kc = 0; kc < 4; ++kc) {
                const int kk = kh * 4 + kc;
                int ao = (lrow << 9) + ((kk * 32 + (lkg << 3)) << 1); ao ^= (lrow & 7) << 4;
                const bf16x8 av = *(const bf16x8*)(smem + C_OFF + ao);
                int wo = (wr << 9) + ((kk * 32 + (lkg << 3)) << 1); wo ^= (wr & 7) << 4;
                const bf16x8 wv = *(const bf16x8*)(smem + WD_OFF + wo);
                accC = __builtin_amdgcn_mfma_f32_16x16x32_bf16(av, wv, accC, 0, 0, 0);
            }
            float* dst = kh ? cs1 : cs0;
            #pragma unroll
            for (int i = 0; i < 4; ++i)
                dst[((lkg << 2) + i) * 33 + (nt << 4) + lrow] = accC[i];
        }
        #pragma unroll
        for (int i = 0; i < 4; ++i)   // D: row=(lane>>4)*4+i (batch), col=lane&15
            gates_st[((lkg << 2) + i) * 132 + n0 + lrow] = accX[i] + accH[i];

        __syncthreads();   // #2: gates staged

        // ---- (5) elementwise T-LSTM update ----
        float cn, hn;
        {
            const float ipre = gates_st[b_ * 132 + jj]      + bI;
            const float fpre = gates_st[b_ * 132 + 32 + jj] + bF;
            const float gpre = gates_st[b_ * 132 + 64 + jj] + bG;
            const float opre = gates_st[b_ * 132 + 96 + jj] + bO;
            const float cspre = cs0[b_ * 33 + jj] + cs1[b_ * 33 + jj] + bD;
            const float gdt  = 1.0f / __logf(2.718281828459045f + dt_cur);
            const float Cs    = tanh_fast(cspre);
            const float cstar = c_reg - Cs + Cs * gdt;
            cn = sigm(fpre) * cstar + sigm(ipre) * tanh_fast(gpre);
            hn = sigm(opre) * tanh_fast(cn);
            c_reg = cn;
        }

        if (t == T_STEPS - 1) {
            out[((size_t)t * BATCH + bb + b_) * HID + jb + jj] = hn;
            const size_t base = (size_t)T_STEPS * BATCH * HID;
            out[base + (size_t)(bb + b_) * HID + jb + jj] = hn;
            out[base + (size_t)BATCH * HID + (size_t)(bb + b_) * HID + jb + jj] = cn;
            break;
        }

        // ---- (6) publish h,c (per-wave) -> drain own stores -> wave flag ----
        {
            const unsigned short hb16 = f2bf(hn), cb16 = f2bf(cn);
            const int oh = __shfl_xor((int)hb16, 1);
            const int oc = __shfl_xor((int)cb16, 1);
            if ((jj & 1) == 0) {
                const unsigned int hw = (unsigned)hb16 | ((unsigned)oh << 16);
                const unsigned int cw = (unsigned)cb16 | ((unsigned)oc << 16);
                const int ei = ((((cur ^ 1) * NGROUP + g) * 8 + s) * 16 + b_) * 16 + (jj >> 1);
                __hip_atomic_store(hb32 + ei, hw, __ATOMIC_RELAXED, __HIP_MEMORY_SCOPE_AGENT);
                __hip_atomic_store(cb32 + ei, cw, __ATOMIC_RELAXED, __HIP_MEMORY_SCOPE_AGENT);
            }
        }
        asm volatile("s_waitcnt vmcnt(0)" ::: "memory");
        if (lane == 0)
            __hip_atomic_store(flags + FLAG_IDX(g, s, wid), (unsigned)(t + 2),
                               __ATOMIC_RELAXED, __HIP_MEMORY_SCOPE_AGENT);

        // ---- (7) off-path: out store + prefetch x(t+1), dt(t+1) ----
        out[((size_t)t * BATCH + bb + b_) * HID + jb + jj] = hn;
        {
            const float* xp = x + ((size_t)(t + 1) * BATCH + bb + lrow) * DIM + (lkg << 3);
            #pragma unroll
            for (int kc = 0; kc < 4; ++kc) {
                xr[2 * kc]     = *(const float4*)(xp + kc * 32);
                xr[2 * kc + 1] = *(const float4*)(xp + kc * 32 + 4);
            }
            dt_cur = dts[(size_t)(bb + b_) * T_STEPS + (t + 1)];
        }
    }
}

extern "C" void kernel_launch(void* const* d_in, const int* in_sizes, int n_in,
                              void* d_out, int out_size, void* d_ws, size_t ws_size,
                              hipStream_t stream) {
    (void)in_sizes; (void)n_in; (void)out_size; (void)ws_size;
    const float* x   = (const float*)d_in[0];
    const float* dts = (const float*)d_in[1];
    const float* h0  = (const float*)d_in[2];
    const float* c0  = (const float*)d_in[3];
    const float* W   = (const float*)d_in[4];
    const float* U   = (const float*)d_in[5];
    const float* bv  = (const float*)d_in[6];
    const float* Wd  = (const float*)d_in[7];
    const float* bd  = (const float*)d_in[8];
    float* out = (float*)d_out;

    char* ws = (char*)d_ws;
    unsigned int* flags = (unsigned int*)ws;                    // 128 lines * 128 B = 16 KB
    unsigned int* hb32  = (unsigned int*)(ws + 16384);          // 2*16*8*16*16 u32 = 256 KB
    unsigned int* cb32  = (unsigned int*)(ws + 16384 + 262144); // 256 KB

    hipMemsetAsync(flags, 0, 16384, stream);
    hipFuncSetAttribute((const void*)tlstm_kernel,
                        hipFuncAttributeMaxDynamicSharedMemorySize, SMEM_TOTAL);
    tlstm_kernel<<<dim3(NBLOCK), dim3(512), SMEM_TOTAL, stream>>>(
        x, dts, h0, c0, W, U, bv, Wd, bd, out, flags, hb32, cb32);
}